// Round 4
// baseline (4341.311 us; speedup 1.0000x reference)
//
#include <hip/hip_runtime.h>
#include <hip/hip_bf16.h>

// BitNet-style ternary MLP: out = relu(x @ Wfc_q^T * s_fc)^2 @ Wproj_q^T * s_proj
// B=8 S=4096 D=2048 H=5120 -> M=32768.
// GEMMs: 256x256 tile, BK=64, 8 waves, 4 phases/K-tile, ONE-PHASE-DEEP REGISTER
// PIPELINE: ds_reads for phase P+1 issue before MFMA(P); waits are counted
// lgkmcnt(8/4) so LDS latency hides under the matrix pipe. Tile-boundary
// staging gate = vmcnt(2) at P3 (T3+T4). Even/odd tile register roles
// (statically named, 2-tile unrolled loop). T2 swizzle via pre-swizzled
// global src; T5 setprio; T1 bijective XCD swizzle.

typedef __attribute__((ext_vector_type(8))) short short8;
typedef __attribute__((ext_vector_type(4))) float f32x4;

#define BM 256
#define BN 256
#define BK 64

__device__ __forceinline__ unsigned short f2bf(float f) {
  unsigned int u = __float_as_uint(f);
  u += 0x7FFFu + ((u >> 16) & 1u);  // RNE
  return (unsigned short)(u >> 16);
}

__device__ __forceinline__ void gload_lds16(const void* gsrc, void* ldst) {
  __builtin_amdgcn_global_load_lds(
      (const __attribute__((address_space(1))) unsigned int*)gsrc,
      (__attribute__((address_space(3))) unsigned int*)ldst, 16, 0, 0);
}

// ---------- pass 1: |w| sum partials (deterministic, fp64 accumulate) ----------
__global__ void k_reduce_abs(const float4* __restrict__ w, int n4,
                             double* __restrict__ partial) {
  __shared__ double sm[256];
  double s = 0.0;
  const int stride = gridDim.x * blockDim.x;
  for (int i = blockIdx.x * blockDim.x + threadIdx.x; i < n4; i += stride) {
    float4 v = w[i];
    s += (double)fabsf(v.x);
    s += (double)fabsf(v.y);
    s += (double)fabsf(v.z);
    s += (double)fabsf(v.w);
  }
  sm[threadIdx.x] = s;
  __syncthreads();
  for (int off = 128; off > 0; off >>= 1) {
    if (threadIdx.x < off) sm[threadIdx.x] += sm[threadIdx.x + off];
    __syncthreads();
  }
  if (threadIdx.x == 0) partial[blockIdx.x] = sm[0];
}

// ---------- pass 2: finalize abs_mean / thr for both weights ----------
__global__ void k_finalize(const double* __restrict__ partial,
                           float* __restrict__ scales, double inv_n) {
  __shared__ double sm[256];
  const int t = threadIdx.x;
  for (int seg = 0; seg < 2; ++seg) {
    const double* p = partial + seg * 1024;
    double s = p[t * 4] + p[t * 4 + 1] + p[t * 4 + 2] + p[t * 4 + 3];
    sm[t] = s;
    __syncthreads();
    for (int off = 128; off > 0; off >>= 1) {
      if (t < off) sm[t] += sm[t + off];
      __syncthreads();
    }
    if (t == 0) {
      float am = (float)(sm[0] * inv_n);
      am = fmaxf(am, 1e-5f);
      scales[seg * 2] = am;             // abs_mean
      scales[seg * 2 + 1] = 0.7f * am;  // threshold
    }
    __syncthreads();
  }
}

// ---------- ternarize: fp32 w -> bf16 q in {-1,0,+1} ----------
__global__ void k_ternarize(const float4* __restrict__ w, ushort4* __restrict__ q,
                            const float* __restrict__ scales, int sidx, int n4) {
  const float thr = scales[sidx * 2 + 1];
  const int stride = gridDim.x * blockDim.x;
  for (int i = blockIdx.x * blockDim.x + threadIdx.x; i < n4; i += stride) {
    float4 v = w[i];
    ushort4 o;
    o.x = v.x > thr ? 0x3F80u : (v.x < -thr ? 0xBF80u : 0u);
    o.y = v.y > thr ? 0x3F80u : (v.y < -thr ? 0xBF80u : 0u);
    o.z = v.z > thr ? 0x3F80u : (v.z < -thr ? 0xBF80u : 0u);
    o.w = v.w > thr ? 0x3F80u : (v.w < -thr ? 0xBF80u : 0u);
    q[i] = o;
  }
}

// ---------- x: fp32 -> bf16 ----------
__global__ void k_f32_to_bf16(const float4* __restrict__ x, ushort4* __restrict__ o,
                              int n4) {
  const int stride = gridDim.x * blockDim.x;
  for (int i = blockIdx.x * blockDim.x + threadIdx.x; i < n4; i += stride) {
    float4 v = x[i];
    ushort4 r;
    r.x = f2bf(v.x);
    r.y = f2bf(v.y);
    r.z = f2bf(v.z);
    r.w = f2bf(v.w);
    o[i] = r;
  }
}

// ================= 256x256 8-wave register-pipelined GEMM =================
// C = A * B^T. A[M][K], B[N][K] bf16; fp32 acc.
// LDS buffer p at p*32768 shorts: A[256][64] @ +0, B[256][64] @ +16384.
// Tile t uses buffer t&1 (nk even -> even tiles buf0, odd tiles buf1).
// Swizzle: LDS linear; src col pre-permuted: LDS[row][c] = G[row][c ^ 8*(row&7)].

#define ST1(Gst, base, r0, k0)                          \
  gload_lds16(Gst + (size_t)(r0) * K + (k0),            \
              (void*)(lptr + (base) + (r0) * 64))

#define ST_AQ0(pp, k0) do { ST1(Ast, (pp)*32768, w8, k0);        ST1(Ast, (pp)*32768, 128 + w8, k0); } while (0)
#define ST_AQ1(pp, k0) do { ST1(Ast, (pp)*32768, 64 + w8, k0);   ST1(Ast, (pp)*32768, 192 + w8, k0); } while (0)
#define ST_BQ0(pp, k0) do { ST1(Bst, (pp)*32768 + 16384, rb, k0);      ST1(Bst, (pp)*32768 + 16384, 128 + rb, k0); } while (0)
#define ST_BQ1(pp, k0) do { ST1(Bst, (pp)*32768 + 16384, 32 + rb, k0); ST1(Bst, (pp)*32768 + 16384, 160 + rb, k0); } while (0)

// 8 ds_read_b128 into an A-half fragment set
#define LDA(dst, p_, qr)                                                       \
  do {                                                                         \
    const unsigned short* ab =                                                 \
        lptr + (p_) * 32768 + (wr * 128 + (qr) * 64 + fr) * 64;                \
    _Pragma("unroll") for (int ri = 0; ri < 4; ++ri) {                         \
      dst[ri][0] = *(const short8*)(ab + ri * 1024 + csw0);                    \
      dst[ri][1] = *(const short8*)(ab + ri * 1024 + csw1);                    \
    }                                                                          \
  } while (0)

// 4 ds_read_b128 into a B-half fragment set
#define LDB(dst, p_, qc)                                                       \
  do {                                                                         \
    const unsigned short* bb =                                                 \
        lptr + (p_) * 32768 + 16384 + (wc * 64 + (qc) * 32 + fr) * 64;         \
    _Pragma("unroll") for (int ci = 0; ci < 2; ++ci) {                         \
      dst[ci][0] = *(const short8*)(bb + ci * 1024 + csw0);                    \
      dst[ci][1] = *(const short8*)(bb + ci * 1024 + csw1);                    \
    }                                                                          \
  } while (0)

#define MFMA_PHASE(afv, bqv, qr, qc)                                           \
  do {                                                                         \
    __builtin_amdgcn_s_setprio(1);                                             \
    _Pragma("unroll") for (int kk = 0; kk < 2; ++kk)                           \
    _Pragma("unroll") for (int ri = 0; ri < 4; ++ri)                           \
    _Pragma("unroll") for (int ci = 0; ci < 2; ++ci)                           \
      acc[(qr) * 4 + ri][(qc) * 2 + ci] =                                      \
          __builtin_amdgcn_mfma_f32_16x16x32_bf16(                             \
              afv[ri][kk], bqv[ci][kk], acc[(qr) * 4 + ri][(qc) * 2 + ci], 0,  \
              0, 0);                                                           \
    __builtin_amdgcn_s_setprio(0);                                             \
  } while (0)

#define BAR()                           \
  do {                                  \
    asm volatile("" ::: "memory");      \
    __builtin_amdgcn_s_barrier();       \
    asm volatile("" ::: "memory");      \
  } while (0)

#define SB() __builtin_amdgcn_sched_barrier(0)
#define WLGKM8() asm volatile("s_waitcnt lgkmcnt(8)" ::: "memory")
#define WLGKM4() asm volatile("s_waitcnt lgkmcnt(4)" ::: "memory")
#define WLGKM0() asm volatile("s_waitcnt lgkmcnt(0)" ::: "memory")

template <int EPI>
__global__ __launch_bounds__(512, 2) void k_gemm_bt(
    const unsigned short* __restrict__ A, const unsigned short* __restrict__ B,
    void* __restrict__ Cout, int M, int N, int K,
    const float* __restrict__ scales, int sidx, int nbx) {
  __shared__ __align__(16) unsigned short lds[2 * 2 * 256 * 64];  // 128 KiB
  unsigned short* lptr = lds;

  const int tid = threadIdx.x;
  const int lane = tid & 63;
  const int w = tid >> 6;   // wave 0..7
  const int wr = w >> 2;    // 0..1 -> 128 rows
  const int wc = w & 3;     // 0..3 -> 64 cols

  // T1: bijective XCD swizzle (gridDim.x % 8 == 0)
  const int nwg = gridDim.x;
  const int cpx = nwg >> 3;
  const int bid = blockIdx.x;
  const int swz = (bid & 7) * cpx + (bid >> 3);
  const int bm = swz / nbx;
  const int bn = swz % nbx;
  const int rowA0 = bm * BM;
  const int rowB0 = bn * BN;

  // staging lane geometry: row within 8-row chunk + pre-swizzled source col
  const int srow = lane >> 3;
  const int scol = ((lane & 7) ^ srow) << 3;  // bf16 elems
  const unsigned short* Ast = A + (size_t)(rowA0 + srow) * K + scol;
  const unsigned short* Bst = B + (size_t)(rowB0 + srow) * K + scol;

  // frag-read lane geometry (read col XORed with 8*(row&7), row&7 == fr&7)
  const int fr = lane & 15;
  const int kgrp = lane >> 4;
  const int csw0 = (kgrp << 3) ^ ((fr & 7) << 3);
  const int csw1 = (32 + (kgrp << 3)) ^ ((fr & 7) << 3);

  const int w8 = w << 3;
  const int rb = ((w >> 2) << 6) + ((w & 3) << 3);

  f32x4 acc[8][4];
#pragma unroll
  for (int i = 0; i < 8; ++i)
#pragma unroll
    for (int j = 0; j < 4; ++j) acc[i][j] = (f32x4){0.f, 0.f, 0.f, 0.f};

  // register fragment double-buffers.
  // even tile (buf0): A0=afA, A1=afB, B0=bqA, B1=bqB
  // odd  tile (buf1): A0=afB, A1=afA, B0=bqA, B1=bqB
  short8 afA[4][2], afB[4][2], bqA[2][2], bqB[2][2];

  const int nk = K / BK;  // even (K=2048 or 5120)

  // prologue: stage tile0 fully + tile1 {BQ0,AQ1}; preload tile0 P1 frags
  ST_BQ0(0, 0);
  ST_AQ1(0, 0);
  ST_AQ0(0, 0);
  ST_BQ1(0, 0);
  ST_BQ0(1, BK);
  ST_AQ1(1, BK);
  asm volatile("s_waitcnt vmcnt(4)" ::: "memory");  // tile0 staged
  BAR();
  LDA(afA, 0, 0);  // A0(t0)
  LDB(bqA, 0, 0);  // B0(t0)  -> 12 lgkm outstanding entering loop

  for (int T = 0; T < nk; T += 2) {
    const int k1 = (T + 1) * BK;
    const int k2 = (T + 2) * BK;
    const int k3 = (T + 3) * BK;
    const bool more = (T + 2) < nk;

    // ================= tile E = T (buf 0) =================
    // ---- P1: q0c0 = afA x bqA; preload A1E->afB ----
    LDA(afB, 0, 1);
    ST_AQ0(1, k1);
    WLGKM8();  // afA,bqA ready (12 preloads done; afB's 8 outstanding)
    SB();
    MFMA_PHASE(afA, bqA, 0, 0);
    SB();
    BAR();
    // ---- P2: q1c0 = afB x bqA; preload B1E->bqB ----
    LDB(bqB, 0, 1);
    ST_BQ1(1, k1);
    WLGKM4();  // afB ready (bqB's 4 outstanding)
    SB();
    MFMA_PHASE(afB, bqA, 1, 0);
    SB();
    BAR();
    // ---- P3: q1c1 = afB x bqB; staging gate for tile T+1 ----
    if (more) ST_BQ0(0, k2);
    WLGKM0();  // bqB ready
    SB();
    MFMA_PHASE(afB, bqB, 1, 1);
    SB();
    if (more) {
      asm volatile("s_waitcnt vmcnt(2)" ::: "memory");  // tile T+1 staged
    } else {
      asm volatile("s_waitcnt vmcnt(0)" ::: "memory");
    }
    BAR();
    // ---- P4: q0c1 = afA x bqB; preload tile O P1 frags (buf1) ----
    LDA(afB, 1, 0);  // A0(O)
    LDB(bqA, 1, 0);  // B0(O)
    if (more) ST_AQ1(0, k2);
    SB();  // operands afA,bqB already clean -> no wait
    MFMA_PHASE(afA, bqB, 0, 1);
    SB();
    BAR();

    // ================= tile O = T+1 (buf 1) =================
    // ---- P1: q0c0 = afB x bqA; preload A1O->afA ----
    LDA(afA, 1, 1);
    if (more) ST_AQ0(0, k2);
    WLGKM8();  // afB,bqA ready
    SB();
    MFMA_PHASE(afB, bqA, 0, 0);
    SB();
    BAR();
    // ---- P2: q1c0 = afA x bqA; preload B1O->bqB ----
    LDB(bqB, 1, 1);
    if (more) ST_BQ1(0, k2);
    WLGKM4();  // afA ready
    SB();
    MFMA_PHASE(afA, bqA, 1, 0);
    SB();
    BAR();
    // ---- P3: q1c1 = afA x bqB; staging gate for tile T+2 ----
    if (more) ST_BQ0(1, k3);
    WLGKM0();  // bqB ready
    SB();
    MFMA_PHASE(afA, bqB, 1, 1);
    SB();
    if (more) {
      asm volatile("s_waitcnt vmcnt(2)" ::: "memory");  // tile T+2 staged
    } else {
      asm volatile("s_waitcnt vmcnt(0)" ::: "memory");
    }
    BAR();
    // ---- P4: q0c1 = afB x bqB; preload tile T+2 P1 frags (buf0) ----
    if (more) {
      LDA(afA, 0, 0);  // A0(E')
      LDB(bqA, 0, 0);  // B0(E')
      ST_AQ1(1, k3);
    }
    SB();
    MFMA_PHASE(afB, bqB, 0, 1);
    SB();
    BAR();
  }

  // epilogue: C/D layout col = lane&15, row = (lane>>4)*4 + q
  const float s = scales[sidx * 2];
  const int crow0 = rowA0 + wr * 128 + (lane >> 4) * 4;
  const int ccol0 = rowB0 + wc * 64 + (lane & 15);
  if (EPI == 0) {
    const float s2 = s * s;
    unsigned short* C = (unsigned short*)Cout;
#pragma unroll
    for (int ri = 0; ri < 8; ++ri)
#pragma unroll
      for (int ci = 0; ci < 4; ++ci)
#pragma unroll
        for (int q = 0; q < 4; ++q) {
          float v = acc[ri][ci][q];
          v = fmaxf(v, 0.0f);
          v = v * v * s2;
          C[(size_t)(crow0 + ri * 16 + q) * N + (ccol0 + ci * 16)] = f2bf(v);
        }
  } else {
    float* C = (float*)Cout;
#pragma unroll
    for (int ri = 0; ri < 8; ++ri)
#pragma unroll
      for (int ci = 0; ci < 4; ++ci)
#pragma unroll
        for (int q = 0; q < 4; ++q)
          C[(size_t)(crow0 + ri * 16 + q) * N + (ccol0 + ci * 16)] =
              acc[ri][ci][q] * s;
  }
}

extern "C" void kernel_launch(void* const* d_in, const int* in_sizes, int n_in,
                              void* d_out, int out_size, void* d_ws, size_t ws_size,
                              hipStream_t stream) {
  const int Mdim = 32768;  // B*S
  const int Ddim = 2048;
  const int Hdim = 5120;
  const int NW = Hdim * Ddim;  // elements per weight

  const float* x = (const float*)d_in[0];
  const float* w_fc = (const float*)d_in[1];
  const float* w_proj = (const float*)d_in[2];
  float* out = (float*)d_out;

  char* ws = (char*)d_ws;
  double* partial = (double*)ws;                          // 16 KB
  float* scales = (float*)(ws + 16384);                   // 4 floats
  unsigned short* wq_fc = (unsigned short*)(ws + 32768);  // 20 MB
  unsigned short* wq_proj = wq_fc + (size_t)NW;           // 20 MB
  unsigned short* xbf = wq_proj + (size_t)NW;             // 128 MB
  unsigned short* hbf = xbf + (size_t)Mdim * Ddim;        // 320 MB

  // 1) abs-mean reductions (deterministic, fp64)
  k_reduce_abs<<<1024, 256, 0, stream>>>((const float4*)w_fc, NW / 4, partial);
  k_reduce_abs<<<1024, 256, 0, stream>>>((const float4*)w_proj, NW / 4,
                                         partial + 1024);
  k_finalize<<<1, 256, 0, stream>>>(partial, scales, 1.0 / (double)NW);

  // 2) ternarize weights -> bf16 q
  k_ternarize<<<2048, 256, 0, stream>>>((const float4*)w_fc, (ushort4*)wq_fc,
                                        scales, 0, NW / 4);
  k_ternarize<<<2048, 256, 0, stream>>>((const float4*)w_proj, (ushort4*)wq_proj,
                                        scales, 1, NW / 4);

  // 3) x -> bf16
  k_f32_to_bf16<<<2048, 256, 0, stream>>>((const float4*)x, (ushort4*)xbf,
                                          (Mdim * Ddim) / 4);

  // 4) h = relu(x @ Wfc^T * s)^2  [M x H] bf16
  k_gemm_bt<0><<<dim3((Hdim / BN) * (Mdim / BM)), 512, 0, stream>>>(
      xbf, wq_fc, hbf, Mdim, Hdim, Ddim, scales, 0, Hdim / BN);

  // 5) out = h @ Wproj^T * s  [M x D] fp32
  k_gemm_bt<1><<<dim3((Ddim / BN) * (Mdim / BM)), 512, 0, stream>>>(
      hbf, wq_proj, out, Mdim, Ddim, Hdim, scales, 1, Ddim / BN);
}

// Round 5
// 1232.190 us; speedup vs baseline: 3.5232x; 3.5232x over previous
//
#include <hip/hip_runtime.h>
#include <hip/hip_bf16.h>

// BitNet-style ternary MLP: out = relu(x @ Wfc_q^T * s_fc)^2 @ Wproj_q^T * s_proj
// B=8 S=4096 D=2048 H=5120 -> M=32768.
// GEMMs: 256x256 tile, BK=64, 8 waves, 4 phases/K-tile (m201 template):
// ds_reads pre-barrier, lgkmcnt(0) post-barrier, A-frags register-held
// (24 ds_read_b128/tile). Staging re-ordered for full HBM-latency slack:
// tile T+1 fully issued by P1(T), tile T+2 groups at P2/P3(T); single
// counted vmcnt(4) gate at P4-end (newest forced load is 3 phases old).
// T2 swizzle via pre-swizzled global src; T5 setprio; T1 bijective XCD swizzle.

typedef __attribute__((ext_vector_type(8))) short short8;
typedef __attribute__((ext_vector_type(4))) float f32x4;

#define BM 256
#define BN 256
#define BK 64

__device__ __forceinline__ unsigned short f2bf(float f) {
  unsigned int u = __float_as_uint(f);
  u += 0x7FFFu + ((u >> 16) & 1u);  // RNE
  return (unsigned short)(u >> 16);
}

__device__ __forceinline__ void gload_lds16(const void* gsrc, void* ldst) {
  __builtin_amdgcn_global_load_lds(
      (const __attribute__((address_space(1))) unsigned int*)gsrc,
      (__attribute__((address_space(3))) unsigned int*)ldst, 16, 0, 0);
}

// ---------- pass 1: |w| sum partials (deterministic, fp64 accumulate) ----------
__global__ void k_reduce_abs(const float4* __restrict__ w, int n4,
                             double* __restrict__ partial) {
  __shared__ double sm[256];
  double s = 0.0;
  const int stride = gridDim.x * blockDim.x;
  for (int i = blockIdx.x * blockDim.x + threadIdx.x; i < n4; i += stride) {
    float4 v = w[i];
    s += (double)fabsf(v.x);
    s += (double)fabsf(v.y);
    s += (double)fabsf(v.z);
    s += (double)fabsf(v.w);
  }
  sm[threadIdx.x] = s;
  __syncthreads();
  for (int off = 128; off > 0; off >>= 1) {
    if (threadIdx.x < off) sm[threadIdx.x] += sm[threadIdx.x + off];
    __syncthreads();
  }
  if (threadIdx.x == 0) partial[blockIdx.x] = sm[0];
}

// ---------- pass 2: finalize abs_mean / thr for both weights ----------
__global__ void k_finalize(const double* __restrict__ partial,
                           float* __restrict__ scales, double inv_n) {
  __shared__ double sm[256];
  const int t = threadIdx.x;
  for (int seg = 0; seg < 2; ++seg) {
    const double* p = partial + seg * 1024;
    double s = p[t * 4] + p[t * 4 + 1] + p[t * 4 + 2] + p[t * 4 + 3];
    sm[t] = s;
    __syncthreads();
    for (int off = 128; off > 0; off >>= 1) {
      if (t < off) sm[t] += sm[t + off];
      __syncthreads();
    }
    if (t == 0) {
      float am = (float)(sm[0] * inv_n);
      am = fmaxf(am, 1e-5f);
      scales[seg * 2] = am;             // abs_mean
      scales[seg * 2 + 1] = 0.7f * am;  // threshold
    }
    __syncthreads();
  }
}

// ---------- ternarize: fp32 w -> bf16 q in {-1,0,+1} ----------
__global__ void k_ternarize(const float4* __restrict__ w, ushort4* __restrict__ q,
                            const float* __restrict__ scales, int sidx, int n4) {
  const float thr = scales[sidx * 2 + 1];
  const int stride = gridDim.x * blockDim.x;
  for (int i = blockIdx.x * blockDim.x + threadIdx.x; i < n4; i += stride) {
    float4 v = w[i];
    ushort4 o;
    o.x = v.x > thr ? 0x3F80u : (v.x < -thr ? 0xBF80u : 0u);
    o.y = v.y > thr ? 0x3F80u : (v.y < -thr ? 0xBF80u : 0u);
    o.z = v.z > thr ? 0x3F80u : (v.z < -thr ? 0xBF80u : 0u);
    o.w = v.w > thr ? 0x3F80u : (v.w < -thr ? 0xBF80u : 0u);
    q[i] = o;
  }
}

// ---------- x: fp32 -> bf16 ----------
__global__ void k_f32_to_bf16(const float4* __restrict__ x, ushort4* __restrict__ o,
                              int n4) {
  const int stride = gridDim.x * blockDim.x;
  for (int i = blockIdx.x * blockDim.x + threadIdx.x; i < n4; i += stride) {
    float4 v = x[i];
    ushort4 r;
    r.x = f2bf(v.x);
    r.y = f2bf(v.y);
    r.z = f2bf(v.z);
    r.w = f2bf(v.w);
    o[i] = r;
  }
}

// ================= 256x256 8-wave pipelined GEMM =================
// C = A * B^T. A[M][K], B[N][K] bf16; fp32 acc.
// LDS per buffer: A[256][64] @ +0, B[256][64] @ +16384 (shorts); dbuf = 128 KiB.
// Swizzle: LDS linear; global src col pre-permuted so that
// LDS[row][c] = G[row][c ^ 8*(row&7)] (elems); frag reads XOR the same.
// Region read-phases (per tile, af0/af1 reg-held): A0:P1, B0:P1, A1:P2, B1:P3.
// Staging: P1(T): AQ0,BQ1 (tile T+1); P2(T): BQ0 (T+2); P3(T): AQ1 (T+2).
// Gate: vmcnt(4) at P4-end forces tile T+1 complete; newest forced load is
// 3 phases old (>= HBM latency).

#define ST1(Gst, base, r0, k0)                          \
  gload_lds16(Gst + (size_t)(r0) * K + (k0),            \
              (void*)(lptr + (base) + (r0) * 64))

#define ST_AQ0(pp, k0) do { ST1(Ast, (pp)*32768, w8, k0);        ST1(Ast, (pp)*32768, 128 + w8, k0); } while (0)
#define ST_AQ1(pp, k0) do { ST1(Ast, (pp)*32768, 64 + w8, k0);   ST1(Ast, (pp)*32768, 192 + w8, k0); } while (0)
#define ST_BQ0(pp, k0) do { ST1(Bst, (pp)*32768 + 16384, rb, k0);      ST1(Bst, (pp)*32768 + 16384, 128 + rb, k0); } while (0)
#define ST_BQ1(pp, k0) do { ST1(Bst, (pp)*32768 + 16384, 32 + rb, k0); ST1(Bst, (pp)*32768 + 16384, 160 + rb, k0); } while (0)

#define LDA(dst, p_, qr)                                                       \
  do {                                                                         \
    const unsigned short* ab =                                                 \
        lptr + (p_) * 32768 + (wr * 128 + (qr) * 64 + fr) * 64;                \
    _Pragma("unroll") for (int ri = 0; ri < 4; ++ri) {                         \
      dst[ri][0] = *(const short8*)(ab + ri * 1024 + csw0);                    \
      dst[ri][1] = *(const short8*)(ab + ri * 1024 + csw1);                    \
    }                                                                          \
  } while (0)

#define LDB(p_, qc)                                                            \
  do {                                                                         \
    const unsigned short* bb =                                                 \
        lptr + (p_) * 32768 + 16384 + (wc * 64 + (qc) * 32 + fr) * 64;         \
    _Pragma("unroll") for (int ci = 0; ci < 2; ++ci) {                         \
      bq[ci][0] = *(const short8*)(bb + ci * 1024 + csw0);                     \
      bq[ci][1] = *(const short8*)(bb + ci * 1024 + csw1);                     \
    }                                                                          \
  } while (0)

#define MFMA_PHASE(afv, qr, qc)                                                \
  do {                                                                         \
    __builtin_amdgcn_s_setprio(1);                                             \
    _Pragma("unroll") for (int kk = 0; kk < 2; ++kk)                           \
    _Pragma("unroll") for (int ri = 0; ri < 4; ++ri)                           \
    _Pragma("unroll") for (int ci = 0; ci < 2; ++ci)                           \
      acc[(qr) * 4 + ri][(qc) * 2 + ci] =                                      \
          __builtin_amdgcn_mfma_f32_16x16x32_bf16(                             \
              afv[ri][kk], bq[ci][kk], acc[(qr) * 4 + ri][(qc) * 2 + ci], 0,   \
              0, 0);                                                           \
    __builtin_amdgcn_s_setprio(0);                                             \
  } while (0)

#define BAR()                           \
  do {                                  \
    asm volatile("" ::: "memory");      \
    __builtin_amdgcn_s_barrier();       \
    asm volatile("" ::: "memory");      \
  } while (0)

#define WAIT_LGKM0() asm volatile("s_waitcnt lgkmcnt(0)" ::: "memory")

template <int EPI>
__global__ __launch_bounds__(512, 2) void k_gemm_bt(
    const unsigned short* __restrict__ A, const unsigned short* __restrict__ B,
    void* __restrict__ Cout, int M, int N, int K,
    const float* __restrict__ scales, int sidx, int nbx) {
  __shared__ __align__(16) unsigned short lds[2 * 2 * 256 * 64];  // 128 KiB
  unsigned short* lptr = lds;

  const int tid = threadIdx.x;
  const int lane = tid & 63;
  const int w = tid >> 6;   // wave 0..7
  const int wr = w >> 2;    // 0..1 -> 128 rows
  const int wc = w & 3;     // 0..3 -> 64 cols

  // T1: bijective XCD swizzle (gridDim.x % 8 == 0)
  const int nwg = gridDim.x;
  const int cpx = nwg >> 3;
  const int bid = blockIdx.x;
  const int swz = (bid & 7) * cpx + (bid >> 3);
  const int bm = swz / nbx;
  const int bn = swz % nbx;
  const int rowA0 = bm * BM;
  const int rowB0 = bn * BN;

  // staging lane geometry: row within 8-row chunk + pre-swizzled source col
  const int srow = lane >> 3;
  const int scol = ((lane & 7) ^ srow) << 3;  // bf16 elems
  const unsigned short* Ast = A + (size_t)(rowA0 + srow) * K + scol;
  const unsigned short* Bst = B + (size_t)(rowB0 + srow) * K + scol;

  // frag-read lane geometry (read col XORed with 8*(row&7), row&7 == fr&7)
  const int fr = lane & 15;
  const int kgrp = lane >> 4;
  const int csw0 = (kgrp << 3) ^ ((fr & 7) << 3);
  const int csw1 = (32 + (kgrp << 3)) ^ ((fr & 7) << 3);

  const int w8 = w << 3;
  const int rb = ((w >> 2) << 6) + ((w & 3) << 3);

  f32x4 acc[8][4];
#pragma unroll
  for (int i = 0; i < 8; ++i)
#pragma unroll
    for (int j = 0; j < 4; ++j) acc[i][j] = (f32x4){0.f, 0.f, 0.f, 0.f};

  short8 af0[4][2], af1[4][2], bq[2][2];

  const int nk = K / BK;

  // prologue (FIFO): tile0 {Bq0,Aq1,Aq0,Bq1}, tile1 {Bq0,Aq1}
  ST_BQ0(0, 0);
  ST_AQ1(0, 0);
  ST_AQ0(0, 0);
  ST_BQ1(0, 0);
  if (nk > 1) {
    ST_BQ0(1, BK);
    ST_AQ1(1, BK);
    asm volatile("s_waitcnt vmcnt(4)" ::: "memory");  // tile0 fully staged
  } else {
    asm volatile("s_waitcnt vmcnt(0)" ::: "memory");
  }
  BAR();

  int p = 0;
  for (int T = 0; T < nk; ++T, p ^= 1) {
    const int pn = p ^ 1;
    const int k1 = (T + 1) * BK;
    const int k2 = (T + 2) * BK;
    const bool more = (T + 2) < nk;

    // ---- P1 (qr=0,qc=0): read A0,B0 pre-barrier; stage AQ0+BQ1 (T+1) ----
    LDA(af0, p, 0);
    LDB(p, 0);
    if (T + 1 < nk) {
      ST_AQ0(pn, k1);
      ST_BQ1(pn, k1);
    }
    asm volatile("s_waitcnt lgkmcnt(8)" ::: "memory");  // partial drain (12 issued)
    BAR();
    WAIT_LGKM0();
    MFMA_PHASE(af0, 0, 0);
    BAR();

    // ---- P2 (qr=1,qc=0): read A1; reuse bq; stage BQ0 (T+2, buf p) ----
    // (B0 of buf p was read only in P1 -> overwrite is 2-barrier safe)
    LDA(af1, p, 1);
    if (more) ST_BQ0(p, k2);
    BAR();
    WAIT_LGKM0();
    MFMA_PHASE(af1, 1, 0);
    BAR();

    // ---- P3 (qr=1,qc=1): read B1; reuse af1; stage AQ1 (T+2, buf p) ----
    // (A1 of buf p was read only in P2 -> overwrite is 2-barrier safe)
    LDB(p, 1);
    if (more) ST_AQ1(p, k2);
    BAR();
    WAIT_LGKM0();
    MFMA_PHASE(af1, 1, 1);
    BAR();

    // ---- P4 (qr=0,qc=1): no reads (af0 held, bq reused); no staging ----
    BAR();
    MFMA_PHASE(af0, 0, 1);
    // tile-boundary gate: force tile T+1 complete (its newest group was
    // issued at P1 of this tile, ~3 phases ago); keep T+2's 4 loads in flight
    if (T + 1 < nk) {
      if (more) {
        asm volatile("s_waitcnt vmcnt(4)" ::: "memory");
      } else {
        asm volatile("s_waitcnt vmcnt(0)" ::: "memory");
      }
    }
    BAR();
  }

  // epilogue: C/D layout col = lane&15, row = (lane>>4)*4 + q
  const float s = scales[sidx * 2];
  const int crow0 = rowA0 + wr * 128 + (lane >> 4) * 4;
  const int ccol0 = rowB0 + wc * 64 + (lane & 15);
  if (EPI == 0) {
    const float s2 = s * s;
    unsigned short* C = (unsigned short*)Cout;
#pragma unroll
    for (int ri = 0; ri < 8; ++ri)
#pragma unroll
      for (int ci = 0; ci < 4; ++ci)
#pragma unroll
        for (int q = 0; q < 4; ++q) {
          float v = acc[ri][ci][q];
          v = fmaxf(v, 0.0f);
          v = v * v * s2;
          C[(size_t)(crow0 + ri * 16 + q) * N + (ccol0 + ci * 16)] = f2bf(v);
        }
  } else {
    float* C = (float*)Cout;
#pragma unroll
    for (int ri = 0; ri < 8; ++ri)
#pragma unroll
      for (int ci = 0; ci < 4; ++ci)
#pragma unroll
        for (int q = 0; q < 4; ++q)
          C[(size_t)(crow0 + ri * 16 + q) * N + (ccol0 + ci * 16)] =
              acc[ri][ci][q] * s;
  }
}

extern "C" void kernel_launch(void* const* d_in, const int* in_sizes, int n_in,
                              void* d_out, int out_size, void* d_ws, size_t ws_size,
                              hipStream_t stream) {
  const int Mdim = 32768;  // B*S
  const int Ddim = 2048;
  const int Hdim = 5120;
  const int NW = Hdim * Ddim;  // elements per weight

  const float* x = (const float*)d_in[0];
  const float* w_fc = (const float*)d_in[1];
  const float* w_proj = (const float*)d_in[2];
  float* out = (float*)d_out;

  char* ws = (char*)d_ws;
  double* partial = (double*)ws;                          // 16 KB
  float* scales = (float*)(ws + 16384);                   // 4 floats
  unsigned short* wq_fc = (unsigned short*)(ws + 32768);  // 20 MB
  unsigned short* wq_proj = wq_fc + (size_t)NW;           // 20 MB
  unsigned short* xbf = wq_proj + (size_t)NW;             // 128 MB
  unsigned short* hbf = xbf + (size_t)Mdim * Ddim;        // 320 MB

  // 1) abs-mean reductions (deterministic, fp64)
  k_reduce_abs<<<1024, 256, 0, stream>>>((const float4*)w_fc, NW / 4, partial);
  k_reduce_abs<<<1024, 256, 0, stream>>>((const float4*)w_proj, NW / 4,
                                         partial + 1024);
  k_finalize<<<1, 256, 0, stream>>>(partial, scales, 1.0 / (double)NW);

  // 2) ternarize weights -> bf16 q
  k_ternarize<<<2048, 256, 0, stream>>>((const float4*)w_fc, (ushort4*)wq_fc,
                                        scales, 0, NW / 4);
  k_ternarize<<<2048, 256, 0, stream>>>((const float4*)w_proj, (ushort4*)wq_proj,
                                        scales, 1, NW / 4);

  // 3) x -> bf16
  k_f32_to_bf16<<<2048, 256, 0, stream>>>((const float4*)x, (ushort4*)xbf,
                                          (Mdim * Ddim) / 4);

  // 4) h = relu(x @ Wfc^T * s)^2  [M x H] bf16
  k_gemm_bt<0><<<dim3((Hdim / BN) * (Mdim / BM)), 512, 0, stream>>>(
      xbf, wq_fc, hbf, Mdim, Hdim, Ddim, scales, 0, Hdim / BN);

  // 5) out = h @ Wproj^T * s  [M x D] fp32
  k_gemm_bt<1><<<dim3((Ddim / BN) * (Mdim / BM)), 512, 0, stream>>>(
      hbf, wq_proj, out, Mdim, Ddim, Hdim, scales, 1, Ddim / BN);
}